// Round 10
// baseline (53.777 us; speedup 1.0000x reference)
//
#include <hip/hip_runtime.h>

#define TEMP 0.7f
#define LOG2E 1.4426950408889634f
#define LN2 0.6931471805599453f
#define NPIX 8192
#define CDIM 128
#define NSTRIP 32               // 32 row/col strips of 256
// sqrt(LOG2E / TEMP): fold exp2-conversion + temperature into bf16 operands
#define FSCALE 1.4356161f
// exp(1/TEMP) = exp(diag) since features are L2-normalized (|F|^2 == 1)
#define EXPDIAG 4.1727352f

typedef __bf16 v8bf __attribute__((ext_vector_type(8)));
typedef float f32x4 __attribute__((ext_vector_type(4)));

// workspace layout (float offsets)
#define OFF_G      0            // 4*128 floats
#define OFF_COUNTS 512          // int[4]
#define OFF_ACC    516          // 1 float
#define OFF_DONE   517          // 1 int
#define OFF_ZERON  520          // zero the first OFF_ZERON floats
#define OFF_PART   1024         // NSTRIP * 8192 floats (rowsum partials)
#define OFF_SWF    (1024 + NSTRIP * NPIX)   // NPIX*CDIM bf16

__global__ __launch_bounds__(256) void k0_zero(float* __restrict__ w) {
    const int i = blockIdx.x * 256 + threadIdx.x;
    if (i < OFF_ZERON) w[i] = 0.0f;
}

// Transpose-build: coalesced feats reads -> LDS tile (128c x 32p, pad 33),
// then emit swizzled bf16 MFMA fragments, class sums G, counts.
__global__ __launch_bounds__(512) void k1_build(
    const float* __restrict__ feats, const int* __restrict__ labels,
    v8bf* __restrict__ swf, float* __restrict__ G, int* __restrict__ counts)
{
    __shared__ float lds[128][33];
    __shared__ int lab_l[32];
    __shared__ float cs[4][4][128];

    const int t = threadIdx.x;
    const int bp = blockIdx.x >> 5;   // b' = row-block in concat order, 0..7
    const int pc = blockIdx.x & 31;   // 32-pixel chunk
    const int b = bp & 3, v = bp >> 2;
    const int bv = b * 2 + v;         // index into feats/labels batch dim
    const int p0 = pc * 32;
    const int nbase = bp * 1024 + p0;

    const float* src = feats + (size_t)bv * CDIM * 1024 + p0;
    const int px = t & 31, c16 = t >> 5;   // 16 channel-groups
#pragma unroll
    for (int i = 0; i < 8; i++) {
        const int c = i * 16 + c16;
        lds[c][px] = src[c * 1024 + px];
    }
    // labels + counts
    if (t < 32) {
        const int lab = labels[bv * 1024 + p0 + t];
        lab_l[t] = lab;
#pragma unroll
        for (int k = 0; k < 4; k++) {
            unsigned long long m = __ballot(lab == k);
            if (t == 0) atomicAdd(&counts[k], (int)__popcll(m));
        }
    }
    __syncthreads();

    // per-class partial sums: 4 quarters of 8 pixels each
    {
        const int cw = t & 127, h = t >> 7;
        float s0 = 0.f, s1 = 0.f, s2 = 0.f, s3 = 0.f;
#pragma unroll
        for (int i = 0; i < 8; i++) {
            const int nl = h * 8 + i;
            const int lab = lab_l[nl];
            const float f = lds[cw][nl];
            s0 += (lab == 0) ? f : 0.f;
            s1 += (lab == 1) ? f : 0.f;
            s2 += (lab == 2) ? f : 0.f;
            s3 += (lab == 3) ? f : 0.f;
        }
        cs[h][0][cw] = s0; cs[h][1][cw] = s1;
        cs[h][2][cw] = s2; cs[h][3][cw] = s3;
    }
    __syncthreads();
    if (t < 128) {
#pragma unroll
        for (int k = 0; k < 4; k++)
            atomicAdd(&G[k * CDIM + t],
                      cs[0][k][t] + cs[1][k][t] + cs[2][k][t] + cs[3][k][t]);
    }

    // swizzled bf16 fragment writes, single pass (512 slots = 8 frags x 64):
    // frag (ctg*4+kk), element q*16+r holds F[ctg*16+r][kk*32+q*8+j]*FSCALE
    {
        const int f = t >> 6, l = t & 63;
        const int ctl = f >> 2, kk = f & 3;
        const int q = l >> 4, r = l & 15;
        const int nl = ctl * 16 + r;
        const int c0 = kk * 32 + q * 8;
        v8bf val;
#pragma unroll
        for (int j = 0; j < 8; j++) val[j] = (__bf16)(lds[c0 + j][nl] * FSCALE);
        const int ctg = (nbase >> 4) + ctl;
        swf[(ctg * 4 + kk) * 64 + l] = val;
    }
}

// Stage one 16-col tile (4 KB, contiguous in swf) into LDS via global_load_lds.
__device__ __forceinline__ void stage_tile(const v8bf* swf, __bf16* ldsbase,
                                           int ct, int wave, int lane)
{
    const char* g = (const char*)swf + ((size_t)ct << 12) + (wave << 10) + (lane << 4);
    char* l = (char*)ldsbase + (wave << 10);
    __builtin_amdgcn_global_load_lds(
        (__attribute__((address_space(1))) void*)(char*)g,
        (__attribute__((address_space(3))) void*)l, 16, 0, 0);
}

// Fused S = F F^T (bf16 MFMA) + exp2 row-sum, SYMMETRIC 256x256 tiles,
// zero atomics: upper-tri 32x32 grid (528 blocks). Block (bi,bj) writes tile
// row-sums to part[bj][rows of strip bi] and (off-diag) col-sums to
// part[bi][rows of strip bj] — every part slot written exactly once.
// 64 KB B-panel staged once via global_load_lds; one barrier; 16 iters
// barrier-free. A = 16 frags (64 VGPR) resident -> 4 MFMA per ds_read_b128
// (R8 evidence: k3 is LDS-read-bound, so reuse is the lever, not FLOPs).
__global__ __launch_bounds__(256, 2) void k3_gemm_expsum(
    const v8bf* __restrict__ swf, float* __restrict__ part)
{
    __shared__ __align__(16) __bf16 bbuf[16][2048];   // 64 KB B-panel
    __shared__ float wcs[4][256];                      // per-wave colsum slices
    const int t = threadIdx.x;
    const int lane = t & 63;
    const int wave = t >> 6;

    // decode upper-triangular block (bi <= bj) over 32 strips
    int rem = blockIdx.x, bi = 0;
    while (rem >= NSTRIP - bi) { rem -= NSTRIP - bi; bi++; }
    const int bj = bi + rem;
    const bool offdiag = (bj != bi);

    const int rt0 = bi * 16 + wave * 4;    // wave's 64 rows = 4 row-tiles
    const int ct0 = bj * 16;               // 16 col-tiles of 16

    // stage the whole B-panel (16 x 4 KB), data never touches VGPRs
#pragma unroll
    for (int j = 0; j < 16; j++)
        stage_tile(swf, &bbuf[j][0], ct0 + j, wave, lane);

    // A fragments: 16 x v8bf = 64 VGPRs, resident
    v8bf a[4][4];
#pragma unroll
    for (int tt = 0; tt < 4; tt++)
#pragma unroll
        for (int kk = 0; kk < 4; kk++)
            a[tt][kk] = swf[((rt0 + tt) * 4 + kk) * 64 + lane];

    float rs[4][4];
#pragma unroll
    for (int tt = 0; tt < 4; tt++)
#pragma unroll
        for (int r = 0; r < 4; r++) rs[tt][r] = 0.f;

    __syncthreads();   // panel staged; no further barriers until epilogue

#pragma unroll 2
    for (int it = 0; it < 16; ++it) {
        const v8bf* bb = (const v8bf*)&bbuf[it][0];
        const v8bf b0 = bb[lane];
        const v8bf b1 = bb[64 + lane];
        const v8bf b2 = bb[128 + lane];
        const v8bf b3 = bb[192 + lane];
        float cc = 0.f;
#pragma unroll
        for (int tt = 0; tt < 4; tt++) {
            f32x4 acc = {0.f, 0.f, 0.f, 0.f};
            acc = __builtin_amdgcn_mfma_f32_16x16x32_bf16(a[tt][0], b0, acc, 0, 0, 0);
            acc = __builtin_amdgcn_mfma_f32_16x16x32_bf16(a[tt][1], b1, acc, 0, 0, 0);
            acc = __builtin_amdgcn_mfma_f32_16x16x32_bf16(a[tt][2], b2, acc, 0, 0, 0);
            acc = __builtin_amdgcn_mfma_f32_16x16x32_bf16(a[tt][3], b3, acc, 0, 0, 0);
            // acc already = S * log2(e) thanks to FSCALE folding
#pragma unroll
            for (int r = 0; r < 4; r++) {
                const float e = __builtin_amdgcn_exp2f(acc[r]);
                rs[tt][r] += e;
                cc += e;
            }
        }
        // wave's 64-row colsum for its 16 cols of tile `it`
        cc += __shfl_xor(cc, 16, 64);
        cc += __shfl_xor(cc, 32, 64);
        if (lane < 16) wcs[wave][it * 16 + lane] = cc;   // unique slot, no race
    }

    // row-sums: reduce across the 16 lanes of each C/D column group
#pragma unroll
    for (int m = 1; m < 16; m <<= 1)
#pragma unroll
        for (int tt = 0; tt < 4; tt++)
#pragma unroll
            for (int r = 0; r < 4; r++)
                rs[tt][r] += __shfl_xor(rs[tt][r], m, 64);

    if ((lane & 15) == 0) {
        const int g = lane >> 4;
        float* dst = part + (size_t)bj * NPIX + bi * 256 + wave * 64;
#pragma unroll
        for (int tt = 0; tt < 4; tt++)
#pragma unroll
            for (int r = 0; r < 4; r++)
                dst[tt * 16 + g * 4 + r] = rs[tt][r];
    }

    // col-sums: combine the 4 wave slices, store to the transposed partial
    if (offdiag) {
        __syncthreads();
        if (t < 256) {
            const float s = wcs[0][t] + wcs[1][t] + wcs[2][t] + wcs[3][t];
            part[(size_t)bi * NPIX + bj * 256 + t] = s;
        }
    }
}

// Per-anchor loss + final divide in the last block (done-counter).
// Block = 4 waves over 64 anchors (one anchor per lane). Each wave sums 8
// of the 32 rowsum partials AND dots 32 of the 128 channels; LDS combine;
// one atomicAdd per block.
__global__ __launch_bounds__(256) void k4_loss(
    const float* __restrict__ feats, const int* __restrict__ labels,
    const float* __restrict__ G, const int* __restrict__ counts,
    const float* __restrict__ part, float* __restrict__ acc,
    int* __restrict__ done, float* __restrict__ out)
{
    __shared__ float pd[4][64];
    __shared__ float pq[4][64];
    const int t = threadIdx.x, lane = t & 63, w = t >> 6;
    const int n0 = blockIdx.x * 64;
    const int bp = n0 >> 10, p0 = n0 & 1023;
    const int bv = ((bp & 3) << 1) + (bp >> 2);
    const int p = p0 + lane;
    const int lab = labels[(bv << 10) + p];

    const float* src = feats + (((size_t)bv * CDIM + w * 32) << 10) + p;
    const float* g0p = G + w * 32;
    float dot = 0.f;
#pragma unroll 8
    for (int c = 0; c < 32; ++c) {
        const float f = src[(size_t)c << 10];
        const float g0 = g0p[c], g1 = g0p[CDIM + c];
        const float g2 = g0p[2 * CDIM + c], g3 = g0p[3 * CDIM + c];
        const float g = (lab == 1) ? g1 : (lab == 2) ? g2 : (lab == 3) ? g3 : g0;
        dot += f * g;
    }
    pd[w][lane] = dot;

    float ps = 0.f;
#pragma unroll
    for (int j = 0; j < 8; ++j)
        ps += part[(size_t)(w * 8 + j) * NPIX + n0 + lane];
    pq[w][lane] = ps;
    __syncthreads();

    if (w == 0) {
        const float den = pq[0][lane] + pq[1][lane] + pq[2][lane] + pq[3][lane]
                        - EXPDIAG;
        const float d = pd[0][lane] + pd[1][lane] + pd[2][lane] + pd[3][lane];
        float loss = 0.f;
        if (lab != 0) {
            const float num = (d - 1.0f) * (1.0f / TEMP);
            const float cnt = (float)(counts[lab] - 1);
            loss = __builtin_amdgcn_logf(den) * LN2 - num / cnt;
        }
#pragma unroll
        for (int m = 1; m < 64; m <<= 1) loss += __shfl_xor(loss, m, 64);
        if (lane == 0) {
            atomicAdd(acc, loss);
            __threadfence();
            const int old = atomicAdd(done, 1);
            if (old == 127) {
                const float tot = atomicAdd(acc, 0.0f);
                const int nv = NPIX - counts[0];
                out[0] = (nv > 0) ? tot / (float)nv : 0.0f;
            }
        }
    }
}

extern "C" void kernel_launch(void* const* d_in, const int* in_sizes, int n_in,
                              void* d_out, int out_size, void* d_ws, size_t ws_size,
                              hipStream_t stream) {
    const float* feats = (const float*)d_in[0];
    const int* labels = (const int*)d_in[1];
    float* out = (float*)d_out;
    float* W = (float*)d_ws;

    float* G      = W + OFF_G;
    int*   counts = (int*)(W + OFF_COUNTS);
    float* acc    = W + OFF_ACC;
    int*   done   = (int*)(W + OFF_DONE);
    float* part   = W + OFF_PART;
    v8bf*  swf    = (v8bf*)(W + OFF_SWF);

    k0_zero<<<3, 256, 0, stream>>>(W);
    k1_build<<<256, 512, 0, stream>>>(feats, labels, swf, G, counts);
    k3_gemm_expsum<<<528, 256, 0, stream>>>(swf, part);
    k4_loss<<<128, 256, 0, stream>>>(feats, labels, G, counts, part, acc, done, out);
}